// Round 10
// baseline (181.636 us; speedup 1.0000x reference)
//
#include <hip/hip_runtime.h>

#define BB 32
#define NN 2048
#define DD 65
#define HH 64
#define ST 68                // padded leading dim (16B-aligned float4 frags)
#define TILE (DD * ST)       // 4420 floats per padded 65x65 matrix
#define CC 32                // x chunks per batch (64 rows each)

__device__ __forceinline__ float4 f4add(float4 a, float4 b) {
  return make_float4(a.x + b.x, a.y + b.y, a.z + b.z, a.w + b.w);
}

// async global->LDS, 16B per lane, wave-uniform LDS base + lane*16
#define GL2LDS(g, l)                                             \
  __builtin_amdgcn_global_load_lds(                              \
      (const __attribute__((address_space(1))) void*)(g),        \
      (__attribute__((address_space(3))) void*)(l), 16, 0, 0)

// ---------------------------------------------------------------------------
// k1: partial Gram of a 64-row chunk ATOMICALLY accumulated into G[b].
// Body is R5-verbatim (4x4 regs, 16x16 threads, f4 staging, 4 blocks/CU);
// only the store changed: P-tile write -> ~4.2K scalar atomicAdd into G.
// Eliminates the 18.1 MB P intermediate (write+read) and the kred kernel.
// fp32 atomic reorder error ~1e-5 in G attenuates to ~1e-10 in out.
// ---------------------------------------------------------------------------
__global__ __launch_bounds__(256, 4) void k1_gram(const float* __restrict__ x,
                                                  float* __restrict__ G) {
  __shared__ __align__(16) float Xl[64 * ST];
  const int t = (int)threadIdx.x;
  const int tx = t & 15, ty = t >> 4;
  const int blk = (int)blockIdx.x;
  const int b = blk >> 5, c = blk & 31;
  const float4* src4 =
      (const float4*)(x + ((size_t)b * NN + (size_t)c * 64) * DD);

  {  // f4 staging: 1040 float4, 5 slots/thread, all in flight
    float4 tmp[5];
#pragma unroll
    for (int q = 0; q < 5; q++) {
      const int i4 = t + 256 * q;
      if (i4 < 1040) tmp[q] = src4[i4];
    }
#pragma unroll
    for (int q = 0; q < 5; q++) {
      const int i4 = t + 256 * q;
      if (i4 < 1040) {
        const int f = 4 * i4;
        const float vv[4] = {tmp[q].x, tmp[q].y, tmp[q].z, tmp[q].w};
#pragma unroll
        for (int j = 0; j < 4; j++) {
          const int r = (f + j) / DD, cc = (f + j) - r * DD;
          Xl[r * ST + cc] = vv[j];
        }
      }
    }
  }
  __syncthreads();

  float g[4][4] = {};
  float g64[4] = {};
  float gcc = 0.f;
  for (int n = 0; n < 64; n++) {
    float rowf[4], colf[4];
    *(float4*)rowf = *(const float4*)&Xl[n * ST + 4 * ty];
    *(float4*)colf = *(const float4*)&Xl[n * ST + 4 * tx];
    const float x64 = Xl[n * ST + 64];  // broadcast, conflict-free
#pragma unroll
    for (int r = 0; r < 4; r++)
#pragma unroll
      for (int cc = 0; cc < 4; cc++)
        g[r][cc] = fmaf(rowf[r], colf[cc], g[r][cc]);
#pragma unroll
    for (int cc = 0; cc < 4; cc++) g64[cc] = fmaf(x64, colf[cc], g64[cc]);
    gcc = fmaf(x64, x64, gcc);
  }

  float* Gp = G + (size_t)b * TILE;
#pragma unroll
  for (int r = 0; r < 4; r++)
#pragma unroll
    for (int cc = 0; cc < 4; cc++)
      atomicAdd(&Gp[(4 * ty + r) * ST + 4 * tx + cc], g[r][cc]);
  if (ty == 0) {
#pragma unroll
    for (int cc = 0; cc < 4; cc++) {
      atomicAdd(&Gp[64 * ST + 4 * tx + cc], g64[cc]);        // G[64][j]
      atomicAdd(&Gp[(4 * tx + cc) * ST + 64], g64[cc]);      // G[j][64]
    }
    if (tx == 0) atomicAdd(&Gp[64 * ST + 64], gcc);
  }
}

// ---------------------------------------------------------------------------
// k2b: ROW-PARALLEL chain. T[i,:] = M[i,:] G Wv^T with M = Wq^T Wk.
// 288 blocks (9 row-groups x 32 batches); R5-verbatim.
// ---------------------------------------------------------------------------
__global__ __launch_bounds__(256) void k2_chain(
    const float* __restrict__ Wq, const float* __restrict__ Wk,
    const float* __restrict__ Wv, const float* __restrict__ G,
    float* __restrict__ Tm) {
  __shared__ __align__(16) float WqL[HH * ST];
  __shared__ __align__(16) float WkL[HH * ST];
  __shared__ __align__(16) float GL[TILE];
  __shared__ __align__(16) float WvT[TILE];
  __shared__ __align__(16) float Mr[8 * ST];
  __shared__ __align__(16) float Rr[8 * ST];

  const int t = (int)threadIdx.x;
  const int tx = t & 31, ty = t >> 5;
  const int blk = (int)blockIdx.x;
  const int b = blk / 9, rg = blk - b * 9;
  const int i = 8 * rg + ty;
  const bool alive = (i < DD);
  const int ic = alive ? i : 0;

  {
    float tq[17], tk[17];
#pragma unroll
    for (int q = 0; q < 17; q++) {
      const int idx = t + 256 * q;
      if (idx < HH * DD) { tq[q] = Wq[idx]; tk[q] = Wk[idx]; }
    }
#pragma unroll
    for (int q = 0; q < 17; q++) {
      const int idx = t + 256 * q;
      if (idx < HH * DD) {
        const int r = idx / DD, cc = idx - r * DD;
        WqL[r * ST + cc] = tq[q];
        WkL[r * ST + cc] = tk[q];
      }
    }
  }
  {
    const float4* Gb4 = (const float4*)(G + (size_t)b * TILE);
    float4 tG[5];
#pragma unroll
    for (int q = 0; q < 5; q++) {
      const int i4 = t + 256 * q;
      if (i4 < TILE / 4) tG[q] = Gb4[i4];
    }
#pragma unroll
    for (int q = 0; q < 5; q++) {
      const int i4 = t + 256 * q;
      if (i4 < TILE / 4) *((float4*)GL + i4) = tG[q];
    }
  }
  {
    float tv[17];
#pragma unroll
    for (int q = 0; q < 17; q++) {
      const int idx = t + 256 * q;
      if (idx < DD * DD) tv[q] = Wv[idx];
    }
#pragma unroll
    for (int q = 0; q < 17; q++) {
      const int idx = t + 256 * q;
      if (idx < DD * DD) {
        const int j = idx / DD, k = idx - j * DD;
        WvT[k * ST + j] = tv[q];
      }
    }
  }
  __syncthreads();

  {
    float m0 = 0.f, m1 = 0.f, m2 = 0.f;
    for (int h = 0; h < HH; h++) {
      const float wq = WqL[h * ST + ic];
      m0 = fmaf(wq, WkL[h * ST + tx], m0);
      m1 = fmaf(wq, WkL[h * ST + tx + 32], m1);
      m2 = fmaf(wq, WkL[h * ST + 64], m2);
    }
    if (alive) {
      Mr[ty * ST + tx] = m0;
      Mr[ty * ST + tx + 32] = m1;
      if (tx == 0) Mr[ty * ST + 64] = m2;
    }
  }
  __syncthreads();

  {
    float r0 = 0.f, r1 = 0.f, r2 = 0.f;
    for (int k = 0; k < DD; k++) {
      const float mm = Mr[ty * ST + k];
      r0 = fmaf(mm, GL[k * ST + tx], r0);
      r1 = fmaf(mm, GL[k * ST + tx + 32], r1);
      r2 = fmaf(mm, GL[k * ST + 64], r2);
    }
    if (alive) {
      Rr[ty * ST + tx] = r0;
      Rr[ty * ST + tx + 32] = r1;
      if (tx == 0) Rr[ty * ST + 64] = r2;
    }
  }
  __syncthreads();

  {
    float t0 = 0.f, t1 = 0.f, t2 = 0.f;
    for (int k = 0; k < DD; k++) {
      const float rv = Rr[ty * ST + k];
      t0 = fmaf(rv, WvT[k * ST + tx], t0);
      t1 = fmaf(rv, WvT[k * ST + tx + 32], t1);
      t2 = fmaf(rv, WvT[k * ST + 64], t2);
    }
    if (alive) {
      float* Tb = Tm + (size_t)b * TILE + (size_t)i * ST;
      Tb[tx] = t0;
      Tb[tx + 32] = t1;
      if (tx == 0) Tb[64] = t2;
    }
  }
}

// ---------------------------------------------------------------------------
// k3: out[b] = x[b] @ T[b]. R5-verbatim (1024 blocks, lb(256,4), async
// GL2LDS Tl, f4-staged Xl, LDS repack epilogue for coalesced f4 stores).
// ---------------------------------------------------------------------------
__global__ __launch_bounds__(256, 4) void k3_out(const float* __restrict__ x,
                                                 const float* __restrict__ Tt,
                                                 float* __restrict__ out) {
  __shared__ __align__(16) float Tl[TILE];       // 17680 B
  __shared__ __align__(16) float Xl[64 * ST];    // 17408 B (reused as Ol)
  const int t = (int)threadIdx.x;
  const int tx = t & 15, ty = t >> 4;
  const int wid = t >> 6, lane = t & 63;
  const int blk = (int)blockIdx.x;
  const int b = blk >> 5;           // 32 blocks per batch
  const int rb = (blk & 31) * 64;
  const float4* Tg4 = (const float4*)(Tt + (size_t)b * TILE);
  const float4* src4 = (const float4*)(x + ((size_t)b * NN + rb) * DD);

#pragma unroll
  for (int q = 0; q < 4; q++) {
    const int s = q * 256 + wid * 64 + lane;          // < 1024
    GL2LDS(Tg4 + s, Tl + (size_t)(q * 256 + wid * 64) * 4);
  }
  {
    const int s = 1024 + wid * 64 + lane;             // tail: 81 slots
    if (s < TILE / 4) GL2LDS(Tg4 + s, Tl + (size_t)(1024 + wid * 64) * 4);
  }
  {
    float4 tmp[5];
#pragma unroll
    for (int q = 0; q < 5; q++) {
      const int i4 = t + 256 * q;
      if (i4 < 1040) tmp[q] = src4[i4];
    }
#pragma unroll
    for (int q = 0; q < 5; q++) {
      const int i4 = t + 256 * q;
      if (i4 < 1040) {
        const int f = 4 * i4;
        const float vv[4] = {tmp[q].x, tmp[q].y, tmp[q].z, tmp[q].w};
#pragma unroll
        for (int j = 0; j < 4; j++) {
          const int r = (f + j) / DD, cc = (f + j) - r * DD;
          Xl[r * ST + cc] = vv[j];
        }
      }
    }
  }
  __syncthreads();  // drains vmcnt -> Tl ready too

  float o[4][4] = {}, o64[4] = {};
  for (int kk = 0; kk < 64; kk += 4) {
    float xa4[4][4], tb4[4][4], t64e[4];
#pragma unroll
    for (int r = 0; r < 4; r++)
      *(float4*)xa4[r] = *(const float4*)&Xl[(4 * ty + r) * ST + kk];
#pragma unroll
    for (int e = 0; e < 4; e++)
      *(float4*)tb4[e] = *(const float4*)&Tl[(kk + e) * ST + 4 * tx];
#pragma unroll
    for (int e = 0; e < 4; e++) t64e[e] = Tl[(kk + e) * ST + 64];
#pragma unroll
    for (int e = 0; e < 4; e++) {
#pragma unroll
      for (int r = 0; r < 4; r++)
#pragma unroll
        for (int cc = 0; cc < 4; cc++)
          o[r][cc] = fmaf(xa4[r][e], tb4[e][cc], o[r][cc]);
#pragma unroll
      for (int r = 0; r < 4; r++)
        o64[r] = fmaf(xa4[r][e], t64e[e], o64[r]);
    }
  }
  {  // k = 64 tail
    float xs[4];
#pragma unroll
    for (int r = 0; r < 4; r++) xs[r] = Xl[(4 * ty + r) * ST + 64];
    float tb[4];
    *(float4*)tb = *(const float4*)&Tl[64 * ST + 4 * tx];
    const float t64 = Tl[64 * ST + 64];
#pragma unroll
    for (int r = 0; r < 4; r++) {
#pragma unroll
      for (int cc = 0; cc < 4; cc++)
        o[r][cc] = fmaf(xs[r], tb[cc], o[r][cc]);
      o64[r] = fmaf(xs[r], t64, o64[r]);
    }
  }

  __syncthreads();
  float* Ol = Xl;   // unpadded [64][65]
#pragma unroll
  for (int r = 0; r < 4; r++) {
#pragma unroll
    for (int cc = 0; cc < 4; cc++)
      Ol[(4 * ty + r) * DD + 4 * tx + cc] = o[r][cc];
  }
  if (tx == 0) {
#pragma unroll
    for (int r = 0; r < 4; r++) Ol[(4 * ty + r) * DD + 64] = o64[r];
  }
  __syncthreads();
  {
    float4* ob4 = (float4*)(out + ((size_t)b * NN + rb) * DD);
    const float4* Ol4 = (const float4*)Ol;
#pragma unroll
    for (int q = 0; q < 5; q++) {
      const int i4 = t + 256 * q;
      if (i4 < (64 * DD) / 4) ob4[i4] = Ol4[i4];
    }
  }
}

extern "C" void kernel_launch(void* const* d_in, const int* in_sizes, int n_in,
                              void* d_out, int out_size, void* d_ws,
                              size_t ws_size, hipStream_t stream) {
  const float* x = (const float*)d_in[0];
  const float* Wq = (const float*)d_in[1];
  const float* Wk = (const float*)d_in[2];
  const float* Wv = (const float*)d_in[3];
  float* out = (float*)d_out;

  // Workspace: G[32 tiles] (0.57 MB, atomically accumulated) + Tm[32 tiles].
  float* G = (float*)d_ws;
  float* Tm = G + (size_t)BB * TILE;

  hipMemsetAsync(G, 0, (size_t)BB * TILE * sizeof(float), stream);
  k1_gram<<<BB * CC, 256, 0, stream>>>(x, G);
  k2_chain<<<BB * 9, 256, 0, stream>>>(Wq, Wk, Wv, G, Tm);
  k3_out<<<BB * CC, 256, 0, stream>>>(x, Tm, out);
  (void)in_sizes; (void)n_in; (void)out_size; (void)ws_size;
}